// Round 9
// baseline (273.839 us; speedup 1.0000x reference)
//
#include <hip/hip_runtime.h>
#include <hip/hip_bf16.h>
#include <stdint.h>

#define BS   16384
#define NC   2000
#define NCP  2048            // padded N (wn zero-filled rows 2000..2047)
#define EMB  512
#define NAUX 5
#define NCHUNK 32            // partial chunks per row: nsplit*4 + wv

typedef __bf16 bf16x8 __attribute__((ext_vector_type(8)));
typedef float  f32x4  __attribute__((ext_vector_type(4)));

// ---------------------------------------------------------------------------
// Kernel 1: row-normalize features (rows [0,BS)) and word_embed ([BS,BS+NC))
// into bf16; zero-fill wn padding rows [NC,NCP). 16 lanes per row.
// ---------------------------------------------------------------------------
__global__ __launch_bounds__(256) void norm_kernel(
    const float* __restrict__ feat, const float* __restrict__ wemb,
    __bf16* __restrict__ fn, __bf16* __restrict__ wn)
{
    const int sub = threadIdx.x & 15;                    // lane-in-row
    const int row = blockIdx.x * 16 + (threadIdx.x >> 4);

    if (row >= BS + NC) {  // padding rows of wn -> zeros (masked in epilogue)
        bf16x8 z = {};
        bf16x8* d = (bf16x8*)(wn + (size_t)(row - BS) * EMB) + sub * 4;
        #pragma unroll
        for (int i = 0; i < 4; ++i) d[i] = z;
        return;
    }
    const float* src;
    __bf16* dst;
    if (row < BS) { src = feat + (size_t)row * EMB;        dst = fn + (size_t)row * EMB; }
    else          { src = wemb + (size_t)(row - BS) * EMB; dst = wn + (size_t)(row - BS) * EMB; }

    const float4* s4 = (const float4*)src + sub * 8;     // 32 floats per lane
    float4 x[8];
    float ss = 0.f;
    #pragma unroll
    for (int i = 0; i < 8; ++i) {
        x[i] = s4[i];
        ss += x[i].x * x[i].x + x[i].y * x[i].y + x[i].z * x[i].z + x[i].w * x[i].w;
    }
    #pragma unroll
    for (int m = 1; m < 16; m <<= 1) ss += __shfl_xor(ss, m, 64);
    const float scale = 1.0f / fmaxf(sqrtf(ss), 1e-12f);

    bf16x8* d = (bf16x8*)dst + sub * 4;
    #pragma unroll
    for (int i = 0; i < 4; ++i) {
        bf16x8 o;
        o[0] = (__bf16)(x[2*i].x   * scale); o[1] = (__bf16)(x[2*i].y   * scale);
        o[2] = (__bf16)(x[2*i].z   * scale); o[3] = (__bf16)(x[2*i].w   * scale);
        o[4] = (__bf16)(x[2*i+1].x * scale); o[5] = (__bf16)(x[2*i+1].y * scale);
        o[6] = (__bf16)(x[2*i+1].z * scale); o[7] = (__bf16)(x[2*i+1].w * scale);
        d[i] = o;
    }
}

// ---------------------------------------------------------------------------
// Kernel 2: barrier-free-K GEMM.
//   Block = 256 thr (4 waves). A stripe = 64 rows x full K=512 staged ONCE
//   into 64 KB chunk-XOR-swizzled LDS (one barrier in the whole kernel).
//   Each wave: 64 rows x 64 cols = 4x4 mfma_f32_16x16x32_bf16 accumulators.
//   B is NOT staged: streamed from global (wn = 2 MB, L2-resident) via a
//   fully unrolled kc loop -> 64 independent dwordx4 loads the compiler can
//   pipeline under the 256-VGPR cap. No inner barriers, no vmcnt(0) drains.
//   XCD swizzle: all 8 n-splits of a stripe land on the same XCD -> A stripe
//   fetched from HBM once, then L2-hit.
// LDS swizzle: 16B chunk c of row r stored at c ^ (r&7); frag reads then hit
// 8 distinct bank groups x 2 lanes = 2-way (free).
// mfma_f32_16x16x32_bf16 verified layouts:
//   A frag: lane(m=lane&15, q=lane>>4) holds A[m][q*8+j]
//   B frag: lane(n=lane&15, q)         holds B[q*8+j][n] = wn[n][q*8+j]
//   C/D:    col(n) = lane&15, row(m) = q*4 + reg
// ---------------------------------------------------------------------------
__global__ __launch_bounds__(256, 2) void main_kernel(
    const __bf16* __restrict__ fn, const __bf16* __restrict__ wn,
    float* __restrict__ es_p, unsigned* __restrict__ key_p)
{
    __shared__ __align__(16) __bf16 As[64 * 512];   // 64 KB

    const int tid    = threadIdx.x;
    const int lane   = tid & 63;
    const int l15    = lane & 15;
    const int quad   = lane >> 4;
    const int wv     = tid >> 6;                 // 0..3
    // XCD swizzle: xcd = bid&7; each XCD owns 32 stripes; the 8 n-splits of a
    // stripe are consecutive on that XCD (idx&7) -> stripe read once from HBM.
    const int xcd    = blockIdx.x & 7;
    const int idx    = blockIdx.x >> 3;          // 0..255
    const int stripe = xcd * 32 + (idx >> 3);    // 0..255
    const int nsplit = idx & 7;                  // 0..7
    const int mBase  = stripe * 64;
    const int colBase = nsplit * 256 + wv * 64;

    // --- Stage A stripe (2 passes; 8 lanes x 16B = contiguous 128B reads) ---
    #pragma unroll
    for (int p = 0; p < 2; ++p) {
        const int row = (tid >> 3) + p * 32;
        const __bf16* g = fn + (size_t)(mBase + row) * EMB;
        #pragma unroll
        for (int i = 0; i < 8; ++i) {
            const int c  = (tid & 7) + i * 8;    // logical 16B chunk 0..63
            const int cp = c ^ (row & 7);        // physical (swizzled)
            *(bf16x8*)(As + row * 512 + cp * 8) = *(const bf16x8*)(g + c * 8);
        }
    }
    __syncthreads();                             // the only barrier

    // --- K loop: fully unrolled, zero barriers ---
    f32x4 acc[4][4] = {};
    const bf16x8* bp[4];
    #pragma unroll
    for (int ni = 0; ni < 4; ++ni)
        bp[ni] = (const bf16x8*)(wn + (size_t)(colBase + ni * 16 + l15) * EMB) + quad;

    #pragma unroll
    for (int kc = 0; kc < 16; ++kc) {
        bf16x8 bF[4], aF[4];
        #pragma unroll
        for (int ni = 0; ni < 4; ++ni)
            bF[ni] = bp[ni][kc * 4];             // global, imm offset kc*64B
        #pragma unroll
        for (int mi = 0; mi < 4; ++mi) {
            const int row = mi * 16 + l15;
            const int c   = (kc * 4 + quad) ^ (row & 7);
            aF[mi] = *(const bf16x8*)(As + row * 512 + c * 8);
        }
        #pragma unroll
        for (int mi = 0; mi < 4; ++mi)
            #pragma unroll
            for (int ni = 0; ni < 4; ++ni)
                acc[mi][ni] = __builtin_amdgcn_mfma_f32_16x16x32_bf16(
                    aF[mi], bF[ni], acc[mi][ni], 0, 0, 0);
    }

    // --- Epilogue: es += exp2((v-1)*20*log2e); packed argmax. ---
    const float C20 = 28.853900817779268f;       // 20*log2(e)
    const int chunk = nsplit * 4 + wv;           // 0..31
    #pragma unroll
    for (int mi = 0; mi < 4; ++mi) {
        float    es[4] = {0.f, 0.f, 0.f, 0.f};
        unsigned km[4] = {0u, 0u, 0u, 0u};
        #pragma unroll
        for (int ni = 0; ni < 4; ++ni) {
            const int col = colBase + ni * 16 + l15;
            const unsigned colenc = 2047u - (unsigned)col;
            const bool valid = (col < NC);
            #pragma unroll
            for (int r = 0; r < 4; ++r) {
                float v = valid ? acc[mi][ni][r] : -3.0f;
                es[r] += exp2f((v - 1.0f) * C20);
                unsigned u = __float_as_uint(v);
                unsigned k = u ^ (unsigned)(((int)u >> 31) | 0x80000000);
                unsigned pk = (k & 0xFFFFF800u) | colenc;  // bigger v, then smaller col
                km[r] = pk > km[r] ? pk : km[r];
            }
        }
        #pragma unroll
        for (int r = 0; r < 4; ++r) {
            #pragma unroll
            for (int m = 1; m < 16; m <<= 1) {
                es[r] += __shfl_xor(es[r], m, 64);
                unsigned x = __shfl_xor(km[r], m, 64);
                km[r] = x > km[r] ? x : km[r];
            }
        }
        if (l15 == 0) {
            #pragma unroll
            for (int r = 0; r < 4; ++r) {
                const int row = mBase + mi * 16 + quad * 4 + r;
                es_p [(size_t)row * NCHUNK + chunk] = es[r];
                key_p[(size_t)row * NCHUNK + chunk] = km[r];
            }
        }
    }
}

// ---------------------------------------------------------------------------
// Kernel 3: gather + finalize. One wave per row:
//   6 dots (label + 5 aux, length 512) -> tgt/auxsum; coalesced [row][32]
//   partial combine; loss/acc; one atomicAdd pair per block.
// ---------------------------------------------------------------------------
__global__ __launch_bounds__(256) void gather_fin_kernel(
    const __bf16* __restrict__ fn, const __bf16* __restrict__ wn,
    const int* __restrict__ label, const int* __restrict__ aux,
    const float* __restrict__ es_p, const unsigned* __restrict__ key_p,
    float* __restrict__ out)
{
    const int lane = threadIdx.x & 63;
    const int wv   = threadIdx.x >> 6;
    const int row  = blockIdx.x * 4 + wv;

    bf16x8 f8 = *((const bf16x8*)fn + (size_t)row * (EMB / 8) + lane);
    float fv[8];
    #pragma unroll
    for (int j = 0; j < 8; ++j) fv[j] = (float)f8[j];

    const int lab = label[row];
    int cols[6];
    cols[0] = lab;
    #pragma unroll
    for (int j = 0; j < NAUX; ++j) cols[j + 1] = aux[row * NAUX + j];

    float res[6];
    #pragma unroll
    for (int c = 0; c < 6; ++c) {
        bf16x8 w8 = *((const bf16x8*)wn + (size_t)cols[c] * (EMB / 8) + lane);
        float d = 0.f;
        #pragma unroll
        for (int j = 0; j < 8; ++j) d += fv[j] * (float)w8[j];
        #pragma unroll
        for (int m = 1; m < 64; m <<= 1) d += __shfl_xor(d, m, 64);
        res[c] = d;
    }
    const float tgt  = res[0] * 20.0f;
    const float auxs = (res[1] + res[2] + res[3] + res[4] + res[5]) * 20.0f;

    // Coalesced combine of the 32 chunk partials (lanes 32-63 duplicate).
    const int c = lane & 31;
    float    es = es_p [(size_t)row * NCHUNK + c];
    unsigned k  = key_p[(size_t)row * NCHUNK + c];
    #pragma unroll
    for (int m = 1; m < 32; m <<= 1) {
        es += __shfl_xor(es, m, 64);
        unsigned x = __shfl_xor(k, m, 64);
        k = x > k ? x : k;
    }
    const int amax = 2047 - (int)(k & 0x7FFu);
    const float loss = 20.0f + logf(es) - 0.95f * tgt - 0.01f * auxs;
    const float acc  = (amax == lab) ? 1.0f : 0.0f;

    __shared__ float sl[4], sa[4];
    if (lane == 0) { sl[wv] = loss; sa[wv] = acc; }
    __syncthreads();
    if (threadIdx.x == 0) {
        atomicAdd(&out[0], (sl[0] + sl[1] + sl[2] + sl[3]) / (float)BS);
        atomicAdd(&out[1], (sa[0] + sa[1] + sa[2] + sa[3]) / (float)BS);
    }
}

// ---------------------------------------------------------------------------
// Workspace layout (bytes):
//   fn    @ 0         (16,777,216)  BS x 512 bf16
//   wn    @ 16777216  ( 2,097,152)  NCP(2048) x 512 bf16 (rows >=2000 zero)
//   es_p  @ 18874368  ( 2,097,152)  [BS][32] f32
//   key_p @ 20971520  ( 2,097,152)  [BS][32] u32
// ---------------------------------------------------------------------------
extern "C" void kernel_launch(void* const* d_in, const int* in_sizes, int n_in,
                              void* d_out, int out_size, void* d_ws, size_t ws_size,
                              hipStream_t stream)
{
    const float* feat  = (const float*)d_in[0];
    const float* wemb  = (const float*)d_in[1];
    const int*   label = (const int*)d_in[2];
    const int*   aux   = (const int*)d_in[3];

    char* ws = (char*)d_ws;
    __bf16*   fn    = (__bf16*)(ws);
    __bf16*   wn    = (__bf16*)(ws + 16777216);
    float*    es_p  = (float*)(ws + 18874368);
    unsigned* key_p = (unsigned*)(ws + 20971520);
    float*    out   = (float*)d_out;

    hipMemsetAsync(out, 0, 2 * sizeof(float), stream);
    hipLaunchKernelGGL(norm_kernel, dim3((BS + NCP) / 16), dim3(256), 0, stream,
                       feat, wemb, fn, wn);
    hipLaunchKernelGGL(main_kernel, dim3((BS / 64) * 8), dim3(256), 0, stream,
                       fn, wn, es_p, key_p);
    hipLaunchKernelGGL(gather_fin_kernel, dim3(BS / 4), dim3(256), 0, stream,
                       fn, wn, label, aux, es_p, key_p, out);
}

// Round 10
// 160.208 us; speedup vs baseline: 1.7093x; 1.7093x over previous
//
#include <hip/hip_runtime.h>
#include <hip/hip_bf16.h>
#include <stdint.h>

#define BS   16384
#define NC   2000
#define NCP  2048            // padded N (wn zero-filled rows 2000..2047)
#define EMB  512
#define NAUX 5
#define NCHUNK 32            // partial chunks per row: nTile*2 + wvN
#define GBLK 4096            // gather_fin blocks (4 rows each)

typedef __bf16 bf16x8 __attribute__((ext_vector_type(8)));
typedef float  f32x4  __attribute__((ext_vector_type(4)));

// ---------------------------------------------------------------------------
// Kernel 1: row-normalize features (rows [0,BS)) and word_embed ([BS,BS+NC))
// into bf16; zero-fill wn padding rows [NC,NCP). 16 lanes per row.
// ---------------------------------------------------------------------------
__global__ __launch_bounds__(256) void norm_kernel(
    const float* __restrict__ feat, const float* __restrict__ wemb,
    __bf16* __restrict__ fn, __bf16* __restrict__ wn)
{
    const int sub = threadIdx.x & 15;                    // lane-in-row
    const int row = blockIdx.x * 16 + (threadIdx.x >> 4);

    if (row >= BS + NC) {  // padding rows of wn -> zeros (masked in epilogue)
        bf16x8 z = {};
        bf16x8* d = (bf16x8*)(wn + (size_t)(row - BS) * EMB) + sub * 4;
        #pragma unroll
        for (int i = 0; i < 4; ++i) d[i] = z;
        return;
    }
    const float* src;
    __bf16* dst;
    if (row < BS) { src = feat + (size_t)row * EMB;        dst = fn + (size_t)row * EMB; }
    else          { src = wemb + (size_t)(row - BS) * EMB; dst = wn + (size_t)(row - BS) * EMB; }

    const float4* s4 = (const float4*)src + sub * 8;     // 32 floats per lane
    float4 x[8];
    float ss = 0.f;
    #pragma unroll
    for (int i = 0; i < 8; ++i) {
        x[i] = s4[i];
        ss += x[i].x * x[i].x + x[i].y * x[i].y + x[i].z * x[i].z + x[i].w * x[i].w;
    }
    #pragma unroll
    for (int m = 1; m < 16; m <<= 1) ss += __shfl_xor(ss, m, 64);
    const float scale = 1.0f / fmaxf(sqrtf(ss), 1e-12f);

    bf16x8* d = (bf16x8*)dst + sub * 4;
    #pragma unroll
    for (int i = 0; i < 4; ++i) {
        bf16x8 o;
        o[0] = (__bf16)(x[2*i].x   * scale); o[1] = (__bf16)(x[2*i].y   * scale);
        o[2] = (__bf16)(x[2*i].z   * scale); o[3] = (__bf16)(x[2*i].w   * scale);
        o[4] = (__bf16)(x[2*i+1].x * scale); o[5] = (__bf16)(x[2*i+1].y * scale);
        o[6] = (__bf16)(x[2*i+1].z * scale); o[7] = (__bf16)(x[2*i+1].w * scale);
        d[i] = o;
    }
}

// ---------------------------------------------------------------------------
// Kernel 2: XCD-swizzled m97 GEMM (r7's proven 65 µs kernel; only change:
// partials stored [row][NCHUNK] for coalesced finalize reads).
//   128x128 tile, BK=64, 4 waves 2x2, global_load_lds width=16 staging with
//   explicit s_waitcnt(0) before the barrier, 16B-chunk XOR bank swizzle.
//   XCD swizzle: xcd=bid&7 owns 16 mTiles, mTile-major -> A fetched from HBM
//   once chip-wide; wn (2 MB) L2-resident.
// mfma_f32_16x16x32_bf16 verified layouts:
//   A frag: lane(m=lane&15, q=lane>>4) holds A[m][q*8+j]
//   B frag: lane(n=lane&15, q)         holds B[q*8+j][n] = wn[n][q*8+j]
//   C/D:    col(n) = lane&15, row(m) = q*4 + reg
// ---------------------------------------------------------------------------
__global__ __launch_bounds__(256) void main_kernel(
    const __bf16* __restrict__ fn, const __bf16* __restrict__ wn,
    float* __restrict__ es_p, unsigned* __restrict__ key_p)
{
    __shared__ __align__(16) __bf16 As[128 * 64];
    __shared__ __align__(16) __bf16 Bs[128 * 64];

    const int tid   = threadIdx.x;
    const int lane  = tid & 63;
    const int l15   = lane & 15;
    const int quad  = lane >> 4;
    const int wv    = tid >> 6;
    const int wvM   = wv >> 1;
    const int wvN   = wv & 1;
    const int xcd   = blockIdx.x & 7;
    const int j     = blockIdx.x >> 3;           // 0..255 within XCD
    const int mTile = xcd * 16 + (j >> 4);       // 0..127
    const int nTile = j & 15;                    // 0..15

    const __bf16* fbase = fn + (size_t)mTile * 128 * EMB;
    const __bf16* wbase = wn + (size_t)nTile * 128 * EMB;

    const int sRowIn = lane >> 3;                 // 0..7
    const int sChunk = (lane & 7) ^ sRowIn;       // logical 16B chunk to fetch
    f32x4 acc[4][4] = {};

    for (int kk = 0; kk < EMB; kk += 64) {
        __syncthreads();                          // previous tile's readers done
        #pragma unroll
        for (int p = 0; p < 4; ++p) {
            const int slot = wv * 4 + p;
            const size_t goff = (size_t)(slot * 8 + sRowIn) * EMB + kk + sChunk * 8;
            __builtin_amdgcn_global_load_lds(
                (const __attribute__((address_space(1))) void*)(fbase + goff),
                (__attribute__((address_space(3))) void*)(As + slot * 512), 16, 0, 0);
            __builtin_amdgcn_global_load_lds(
                (const __attribute__((address_space(1))) void*)(wbase + goff),
                (__attribute__((address_space(3))) void*)(Bs + slot * 512), 16, 0, 0);
        }
        __builtin_amdgcn_s_waitcnt(0);            // drain global->LDS DMA
        __syncthreads();                          // staged tile visible to all

        #pragma unroll
        for (int kc = 0; kc < 2; ++kc) {
            bf16x8 aF[4], bF[4];
            #pragma unroll
            for (int i = 0; i < 4; ++i) {
                const int ar = wvM * 64 + i * 16 + l15;
                const int br = wvN * 64 + i * 16 + l15;
                const int ca = ((kc * 4 + quad) ^ (ar & 7)) * 8;
                const int cb = ((kc * 4 + quad) ^ (br & 7)) * 8;
                aF[i] = *(const bf16x8*)(As + ar * 64 + ca);
                bF[i] = *(const bf16x8*)(Bs + br * 64 + cb);
            }
            #pragma unroll
            for (int mi = 0; mi < 4; ++mi)
                #pragma unroll
                for (int ni = 0; ni < 4; ++ni)
                    acc[mi][ni] = __builtin_amdgcn_mfma_f32_16x16x32_bf16(
                        aF[mi], bF[ni], acc[mi][ni], 0, 0, 0);
        }
    }

    // Epilogue: es += exp2((v-1)*20*log2e); packed argmax; [row][32] partials.
    const float C20 = 28.853900817779268f;  // 20*log2(e)
    const int chunk = nTile * 2 + wvN;
    #pragma unroll
    for (int mi = 0; mi < 4; ++mi) {
        float    es[4] = {0.f, 0.f, 0.f, 0.f};
        unsigned km[4] = {0u, 0u, 0u, 0u};
        #pragma unroll
        for (int ni = 0; ni < 4; ++ni) {
            const int col = nTile * 128 + wvN * 64 + ni * 16 + l15;
            const unsigned colenc = 2047u - (unsigned)col;
            const bool valid = (col < NC);
            #pragma unroll
            for (int r = 0; r < 4; ++r) {
                float v = valid ? acc[mi][ni][r] : -3.0f;
                es[r] += exp2f((v - 1.0f) * C20);
                unsigned u = __float_as_uint(v);
                unsigned k = u ^ (unsigned)(((int)u >> 31) | 0x80000000);
                unsigned pk = (k & 0xFFFFF800u) | colenc;  // bigger v, then smaller col
                km[r] = pk > km[r] ? pk : km[r];
            }
        }
        #pragma unroll
        for (int r = 0; r < 4; ++r) {
            #pragma unroll
            for (int m = 1; m < 16; m <<= 1) {
                es[r] += __shfl_xor(es[r], m, 64);
                unsigned x = __shfl_xor(km[r], m, 64);
                km[r] = x > km[r] ? x : km[r];
            }
        }
        if (l15 == 0) {
            #pragma unroll
            for (int r = 0; r < 4; ++r) {
                const int row = mTile * 128 + wvM * 64 + mi * 16 + quad * 4 + r;
                es_p [(size_t)row * NCHUNK + chunk] = es[r];
                key_p[(size_t)row * NCHUNK + chunk] = km[r];
            }
        }
    }
}

// ---------------------------------------------------------------------------
// Kernel 3: gather + finalize. One wave per row: 6 dots (label + 5 aux),
// coalesced [row][32] partial combine, loss/acc, per-block partial (plain
// stores — NO same-address atomics).
// ---------------------------------------------------------------------------
__global__ __launch_bounds__(256) void gather_fin_kernel(
    const __bf16* __restrict__ fn, const __bf16* __restrict__ wn,
    const int* __restrict__ label, const int* __restrict__ aux,
    const float* __restrict__ es_p, const unsigned* __restrict__ key_p,
    float* __restrict__ blkpart)
{
    const int lane = threadIdx.x & 63;
    const int wv   = threadIdx.x >> 6;
    const int row  = blockIdx.x * 4 + wv;

    bf16x8 f8 = *((const bf16x8*)fn + (size_t)row * (EMB / 8) + lane);
    float fv[8];
    #pragma unroll
    for (int j = 0; j < 8; ++j) fv[j] = (float)f8[j];

    const int lab = label[row];
    int cols[6];
    cols[0] = lab;
    #pragma unroll
    for (int j = 0; j < NAUX; ++j) cols[j + 1] = aux[row * NAUX + j];

    float res[6];
    #pragma unroll
    for (int c = 0; c < 6; ++c) {
        bf16x8 w8 = *((const bf16x8*)wn + (size_t)cols[c] * (EMB / 8) + lane);
        float d = 0.f;
        #pragma unroll
        for (int j = 0; j < 8; ++j) d += fv[j] * (float)w8[j];
        #pragma unroll
        for (int m = 1; m < 64; m <<= 1) d += __shfl_xor(d, m, 64);
        res[c] = d;
    }
    const float tgt  = res[0] * 20.0f;
    const float auxs = (res[1] + res[2] + res[3] + res[4] + res[5]) * 20.0f;

    // Coalesced combine of the 32 chunk partials (lanes 32-63 duplicate).
    const int c = lane & 31;
    float    es = es_p [(size_t)row * NCHUNK + c];
    unsigned k  = key_p[(size_t)row * NCHUNK + c];
    #pragma unroll
    for (int m = 1; m < 32; m <<= 1) {
        es += __shfl_xor(es, m, 64);
        unsigned x = __shfl_xor(k, m, 64);
        k = x > k ? x : k;
    }
    const int amax = 2047 - (int)(k & 0x7FFu);
    const float loss = 20.0f + logf(es) - 0.95f * tgt - 0.01f * auxs;
    const float acc  = (amax == lab) ? 1.0f : 0.0f;

    __shared__ float sl[4], sa[4];
    if (lane == 0) { sl[wv] = loss; sa[wv] = acc; }
    __syncthreads();
    if (threadIdx.x == 0) {
        blkpart[blockIdx.x]        = sl[0] + sl[1] + sl[2] + sl[3];
        blkpart[GBLK + blockIdx.x] = sa[0] + sa[1] + sa[2] + sa[3];
    }
}

// ---------------------------------------------------------------------------
// Kernel 4: reduce 4096 block partials -> (loss, acc). One block.
// ---------------------------------------------------------------------------
__global__ __launch_bounds__(256) void fin2_kernel(
    const float* __restrict__ blkpart, float* __restrict__ out)
{
    float l = 0.f, a = 0.f;
    for (int i = threadIdx.x; i < GBLK; i += 256) {
        l += blkpart[i];
        a += blkpart[GBLK + i];
    }
    #pragma unroll
    for (int m = 1; m < 64; m <<= 1) {
        l += __shfl_xor(l, m, 64);
        a += __shfl_xor(a, m, 64);
    }
    __shared__ float sl[4], sa[4];
    const int wv = threadIdx.x >> 6;
    if ((threadIdx.x & 63) == 0) { sl[wv] = l; sa[wv] = a; }
    __syncthreads();
    if (threadIdx.x == 0) {
        out[0] = (sl[0] + sl[1] + sl[2] + sl[3]) / (float)BS;
        out[1] = (sa[0] + sa[1] + sa[2] + sa[3]) / (float)BS;
    }
}

// ---------------------------------------------------------------------------
// Workspace layout (bytes):
//   fn      @ 0         (16,777,216)  BS x 512 bf16
//   wn      @ 16777216  ( 2,097,152)  NCP(2048) x 512 bf16 (rows >=2000 zero)
//   es_p    @ 18874368  ( 2,097,152)  [BS][32] f32
//   key_p   @ 20971520  ( 2,097,152)  [BS][32] u32
//   blkpart @ 23068672  (    32,768)  [2][4096] f32
// ---------------------------------------------------------------------------
extern "C" void kernel_launch(void* const* d_in, const int* in_sizes, int n_in,
                              void* d_out, int out_size, void* d_ws, size_t ws_size,
                              hipStream_t stream)
{
    const float* feat  = (const float*)d_in[0];
    const float* wemb  = (const float*)d_in[1];
    const int*   label = (const int*)d_in[2];
    const int*   aux   = (const int*)d_in[3];

    char* ws = (char*)d_ws;
    __bf16*   fn      = (__bf16*)(ws);
    __bf16*   wn      = (__bf16*)(ws + 16777216);
    float*    es_p    = (float*)(ws + 18874368);
    unsigned* key_p   = (unsigned*)(ws + 20971520);
    float*    blkpart = (float*)(ws + 23068672);
    float*    out     = (float*)d_out;

    hipLaunchKernelGGL(norm_kernel, dim3((BS + NCP) / 16), dim3(256), 0, stream,
                       feat, wemb, fn, wn);
    hipLaunchKernelGGL(main_kernel, dim3((BS / 128) * (NCP / 128)), dim3(256), 0, stream,
                       fn, wn, es_p, key_p);
    hipLaunchKernelGGL(gather_fin_kernel, dim3(GBLK), dim3(256), 0, stream,
                       fn, wn, label, aux, es_p, key_p, blkpart);
    hipLaunchKernelGGL(fin2_kernel, dim3(1), dim3(256), 0, stream, blkpart, out);
}